// Round 3
// baseline (445.852 us; speedup 1.0000x reference)
//
#include <hip/hip_runtime.h>
#include <hip/hip_bf16.h>

#define DIN   256
#define HID   512
#define NBAT  32
#define NSEQ  1024
#define SCALEF (1.0f / 2304.0f)
#define NEGC  9e15f

typedef __attribute__((ext_vector_type(4))) float f32x4;
typedef __attribute__((ext_vector_type(8))) short bf16x8;
typedef unsigned short u16;

__device__ __forceinline__ u16 f2bf(float f) {
    union { float f; unsigned u; } v; v.f = f;
    unsigned r = v.u + 0x7fffu + ((v.u >> 16) & 1u);   // RTNE
    return (u16)(r >> 16);
}

__device__ __forceinline__ float bf2f(u16 b) {
    union { unsigned u; float f; } v; v.u = ((unsigned)b) << 16;
    return v.f;
}

__device__ __forceinline__ void g2lds16(const void* g, void* l) {
    __builtin_amdgcn_global_load_lds(
        (const __attribute__((address_space(1))) void*)g,
        (__attribute__((address_space(3))) void*)l,
        16, 0, 0);
}

// ---------------------------------------------------------------------------
// prep: x (f32) -> bf16
__global__ __launch_bounds__(256) void prep_x(const float* __restrict__ x,
                                              u16* __restrict__ xb) {
    long i = (long)blockIdx.x * 256 + threadIdx.x;     // float4 index
    const long n4 = (long)NBAT * NSEQ * DIN / 4;       // 2,097,152
    if (i < n4) {
        float4 v = ((const float4*)x)[i];
        ushort4 o;
        o.x = f2bf(v.x); o.y = f2bf(v.y); o.z = f2bf(v.z); o.w = f2bf(v.w);
        ((ushort4*)xb)[i] = o;
    }
}

// prep: W^T concat [v|k|q] -> bf16 [1536][256]; bias concat f32 [1536]
__global__ __launch_bounds__(256) void prep_w(
    const float* __restrict__ Wv, const float* __restrict__ bv,
    const float* __restrict__ Wk, const float* __restrict__ bk,
    const float* __restrict__ Wq, const float* __restrict__ bq,
    u16* __restrict__ Wtb, float* __restrict__ biascat) {
    int i = blockIdx.x * 256 + threadIdx.x;
    if (i < 1536 * 256) {
        int n = i >> 8, k = i & 255;
        const float* W = (n < 512) ? Wv : ((n < 1024) ? Wk : Wq);
        Wtb[i] = f2bf(W[k * 512 + (n & 511)]);         // Wtb[n][k] = W[k][n%512]
    }
    if (i < 1536) {
        biascat[i] = (i < 512) ? bv[i] : ((i < 1024) ? bk[i - 512] : bq[i - 1024]);
    }
}

// ---------------------------------------------------------------------------
// 128x128-tile bf16 MFMA GEMM, both operands K-contiguous row-major.
// C[i][j] = sum_k A[i][k] * Bt[j][k].   M,N multiples of 128, K multiple of 32.
// EPI 0: qkv   (bias+relu, *SCALE for cols>=1024, store bf16)
// EPI 1: plain bf16 store (scores)
// EPI 2: relu + f32 store (output)
template<int EPI>
__global__ __launch_bounds__(256) void gemm128(
    const u16* __restrict__ A, int lda, long sA,
    const u16* __restrict__ Bt, int ldb, long sB,
    void* __restrict__ Cv, int ldc, long sC,
    int K, const float* __restrict__ bias) {
    __shared__ u16 lA[128 * 32];
    __shared__ u16 lB[128 * 32];
    const int t = threadIdx.x;
    const int lane = t & 63;
    const int w = t >> 6;
    const int b = blockIdx.z;
    const u16* Ab = A + (long)b * sA;
    const u16* Bb = Bt + (long)b * sB;
    const int bm = blockIdx.x * 128, bn = blockIdx.y * 128;

    // staging: thread t loads 16B chunk (t&3) of row (t>>2), rows +0 and +64
    const int srow = t >> 2;
    const int soff = (t & 3) * 8;
    const u16* gA0 = Ab + (long)(bm + srow) * lda + soff;
    const u16* gA1 = Ab + (long)(bm + srow + 64) * lda + soff;
    const u16* gB0 = Bb + (long)(bn + srow) * ldb + soff;
    const u16* gB1 = Bb + (long)(bn + srow + 64) * ldb + soff;

    const int wr = (w >> 1) * 64, wc = (w & 1) * 64;   // wave sub-tile origin
    const int frow = lane & 15, fk = (lane >> 4) * 8;  // fragment lane mapping

    f32x4 acc[4][4] = {};

    for (int k0 = 0; k0 < K; k0 += 32) {
        __syncthreads();
        g2lds16(gA0 + k0, &lA[t * 8]);
        g2lds16(gA1 + k0, &lA[2048 + t * 8]);
        g2lds16(gB0 + k0, &lB[t * 8]);
        g2lds16(gB1 + k0, &lB[2048 + t * 8]);
        __syncthreads();   // compiler drains vmcnt before barrier

        bf16x8 af[4], bfr[4];
#pragma unroll
        for (int i = 0; i < 4; ++i)
            af[i] = *(const bf16x8*)&lA[(wr + i * 16 + frow) * 32 + fk];
#pragma unroll
        for (int j = 0; j < 4; ++j)
            bfr[j] = *(const bf16x8*)&lB[(wc + j * 16 + frow) * 32 + fk];
#pragma unroll
        for (int i = 0; i < 4; ++i)
#pragma unroll
            for (int j = 0; j < 4; ++j)
                acc[i][j] = __builtin_amdgcn_mfma_f32_16x16x32_bf16(
                    af[i], bfr[j], acc[i][j], 0, 0, 0);
    }

    // epilogue: C/D map col=lane&15, row=(lane>>4)*4+reg  [m89-verified]
    const int crow0 = bm + wr + (lane >> 4) * 4;
    const int ccol0 = bn + wc + (lane & 15);
#pragma unroll
    for (int i = 0; i < 4; ++i) {
#pragma unroll
        for (int j = 0; j < 4; ++j) {
            int col = ccol0 + j * 16;
#pragma unroll
            for (int r = 0; r < 4; ++r) {
                int row = crow0 + i * 16 + r;
                float v = acc[i][j][r];
                if (EPI == 0) {
                    v += bias[col];
                    v = v > 0.0f ? v : 0.0f;
                    if (col >= 1024) v *= SCALEF;      // fold SCALE into q
                    ((u16*)Cv)[(long)b * sC + (long)row * ldc + col] = f2bf(v);
                } else if (EPI == 1) {
                    ((u16*)Cv)[(long)b * sC + (long)row * ldc + col] = f2bf(v);
                } else {
                    ((float*)Cv)[(long)b * sC + (long)row * ldc + col] =
                        v > 0.0f ? v : 0.0f;
                }
            }
        }
    }
}

// ---------------------------------------------------------------------------
// v [b][n][h] (inside qkv, cols 0..511) -> vt [b][h][n]   (bf16)
__global__ __launch_bounds__(256) void transpose_v(const u16* __restrict__ qkv,
                                                   u16* __restrict__ vt) {
    __shared__ u16 tile[64][72];   // stride 144B = 16B-aligned, bank-decorrelated
    const int t = threadIdx.x;
    const int b = blockIdx.z;
    const int n0 = blockIdx.x * 64, h0 = blockIdx.y * 64;
    const u16* src = qkv + (long)(b * NSEQ + n0) * 1536 + h0;
#pragma unroll
    for (int it = 0; it < 2; ++it) {
        int n = (t >> 3) + it * 32;
        int hc = (t & 7) * 8;
        *(bf16x8*)&tile[n][hc] = *(const bf16x8*)&src[(long)n * 1536 + hc];
    }
    __syncthreads();
    u16* dst = vt + ((long)b * HID + h0) * NSEQ + n0;
#pragma unroll
    for (int it = 0; it < 2; ++it) {
        int h = (t >> 3) + it * 32;
        int nc = (t & 7) * 8;
        bf16x8 v;
#pragma unroll
        for (int j = 0; j < 8; ++j) v[j] = (short)tile[nc + j][h];
        *(bf16x8*)&dst[(long)h * NSEQ + nc] = v;
    }
}

// ---------------------------------------------------------------------------
// one block per score row: masked softmax, S is bf16, store P as bf16
__global__ __launch_bounds__(256) void softmax_mask(
    const u16* __restrict__ S, const float* __restrict__ mask,
    u16* __restrict__ P) {
    const long row = blockIdx.x;
    const int t = threadIdx.x;
    ushort4 sv = ((const ushort4*)(S + row * NSEQ))[t];
    float4 mv = ((const float4*)(mask + row * NSEQ))[t];
    float l0 = mv.x * bf2f(sv.x) - NEGC * (1.0f - mv.x);
    float l1 = mv.y * bf2f(sv.y) - NEGC * (1.0f - mv.y);
    float l2 = mv.z * bf2f(sv.z) - NEGC * (1.0f - mv.z);
    float l3 = mv.w * bf2f(sv.w) - NEGC * (1.0f - mv.w);

    float mx = fmaxf(fmaxf(l0, l1), fmaxf(l2, l3));
#pragma unroll
    for (int off = 32; off; off >>= 1) mx = fmaxf(mx, __shfl_xor(mx, off));
    __shared__ float redm[4];
    if ((t & 63) == 0) redm[t >> 6] = mx;
    __syncthreads();
    mx = fmaxf(fmaxf(redm[0], redm[1]), fmaxf(redm[2], redm[3]));

    float e0 = __expf(l0 - mx), e1 = __expf(l1 - mx);
    float e2 = __expf(l2 - mx), e3 = __expf(l3 - mx);
    float sum = (e0 + e1) + (e2 + e3);
#pragma unroll
    for (int off = 32; off; off >>= 1) sum += __shfl_xor(sum, off);
    __shared__ float reds[4];
    if ((t & 63) == 0) reds[t >> 6] = sum;
    __syncthreads();
    sum = (reds[0] + reds[1]) + (reds[2] + reds[3]);

    float inv = 1.0f / sum;
    ushort4 o;
    o.x = f2bf(e0 * inv); o.y = f2bf(e1 * inv);
    o.z = f2bf(e2 * inv); o.w = f2bf(e3 * inv);
    ((ushort4*)(P + row * NSEQ))[t] = o;
}

// ---------------------------------------------------------------------------
extern "C" void kernel_launch(void* const* d_in, const int* in_sizes, int n_in,
                              void* d_out, int out_size, void* d_ws, size_t ws_size,
                              hipStream_t stream) {
    const float* x    = (const float*)d_in[0];
    const float* mask = (const float*)d_in[1];
    const float* Wv   = (const float*)d_in[2];
    const float* bv   = (const float*)d_in[3];
    const float* Wk   = (const float*)d_in[4];
    const float* bk   = (const float*)d_in[5];
    const float* Wq   = (const float*)d_in[6];
    const float* bq   = (const float*)d_in[7];
    float* out = (float*)d_out;

    char* ws = (char*)d_ws;
    u16*   xb      = (u16*)ws;   ws += (long)NBAT * NSEQ * DIN * 2;      // 16 MB
    u16*   Wtb     = (u16*)ws;   ws += (long)1536 * 256 * 2;             // 768 KB
    float* biascat = (float*)ws; ws += 1536 * 4;
    u16*   qkv     = (u16*)ws;   ws += (long)NBAT * NSEQ * 1536 * 2;     // 96 MB
    u16*   vt      = (u16*)ws;   ws += (long)NBAT * HID * NSEQ * 2;      // 32 MB

    // pick largest chunk CH (batches per S/P pass) that fits remaining ws
    size_t used = (size_t)(ws - (char*)d_ws);
    size_t rem = (ws_size > used) ? ws_size - used : 0;
    int CH = 1;
    for (int c = 32; c >= 1; c >>= 1) {
        if ((size_t)c * NSEQ * NSEQ * 4 <= rem) { CH = c; break; }  // S+P = 4B/elem
    }
    u16* S = (u16*)ws;           ws += (long)CH * NSEQ * NSEQ * 2;
    u16* P = (u16*)ws;           ws += (long)CH * NSEQ * NSEQ * 2;

    prep_x<<<8192, 256, 0, stream>>>(x, xb);
    prep_w<<<1536, 256, 0, stream>>>(Wv, bv, Wk, bk, Wq, bq, Wtb, biascat);

    // qkv projections: [32768,256] x [1536,256]^T -> [32768,1536] bf16
    gemm128<0><<<dim3(256, 12, 1), 256, 0, stream>>>(
        xb, 256, 0L, Wtb, 256, 0L, qkv, 1536, 0L, 256, biascat);

    transpose_v<<<dim3(16, 8, NBAT), 256, 0, stream>>>(qkv, vt);

    const long sQKV = (long)NSEQ * 1536;
    for (int c = 0; c < NBAT / CH; ++c) {
        const u16* qb = qkv + (long)c * CH * sQKV + 1024;   // q cols [1024,1536)
        const u16* kb = qkv + (long)c * CH * sQKV + 512;    // k cols [512,1024)
        // scores: per-batch [1024,512] x [1024,512]^T -> [1024,1024] bf16
        gemm128<1><<<dim3(8, 8, CH), 256, 0, stream>>>(
            qb, 1536, sQKV, kb, 1536, sQKV, S, NSEQ, (long)NSEQ * NSEQ, 512, nullptr);
        softmax_mask<<<CH * NSEQ, 256, 0, stream>>>(
            S, mask + (long)c * CH * NSEQ * NSEQ, P);
        // out: per-batch [1024,1024] x [512,1024]^T -> [1024,512] f32, relu
        gemm128<2><<<dim3(8, 4, CH), 256, 0, stream>>>(
            P, NSEQ, (long)NSEQ * NSEQ, vt, NSEQ, (long)HID * NSEQ,
            out + (long)c * CH * NSEQ * HID, HID, (long)NSEQ * HID, NSEQ, nullptr);
    }
}

// Round 4
// 426.525 us; speedup vs baseline: 1.0453x; 1.0453x over previous
//
#include <hip/hip_runtime.h>
#include <hip/hip_bf16.h>

#define DIN   256
#define HID   512
#define NBAT  32
#define NSEQ  1024
#define SCALEF (1.0f / 2304.0f)
#define NEGC  9e15f

typedef __attribute__((ext_vector_type(4))) float f32x4;
typedef __attribute__((ext_vector_type(8))) short bf16x8;
typedef unsigned short u16;

__device__ __forceinline__ u16 f2bf(float f) {
    union { float f; unsigned u; } v; v.f = f;
    unsigned r = v.u + 0x7fffu + ((v.u >> 16) & 1u);   // RTNE
    return (u16)(r >> 16);
}

__device__ __forceinline__ float bf2f(u16 b) {
    union { unsigned u; float f; } v; v.u = ((unsigned)b) << 16;
    return v.f;
}

__device__ __forceinline__ void g2lds16(const void* g, void* l) {
    __builtin_amdgcn_global_load_lds(
        (const __attribute__((address_space(1))) void*)g,
        (__attribute__((address_space(3))) void*)l,
        16, 0, 0);
}

// ---------------------------------------------------------------------------
// prep: x (f32) -> bf16
__global__ __launch_bounds__(256) void prep_x(const float* __restrict__ x,
                                              u16* __restrict__ xb) {
    long i = (long)blockIdx.x * 256 + threadIdx.x;     // float4 index
    const long n4 = (long)NBAT * NSEQ * DIN / 4;
    if (i < n4) {
        float4 v = ((const float4*)x)[i];
        ushort4 o;
        o.x = f2bf(v.x); o.y = f2bf(v.y); o.z = f2bf(v.z); o.w = f2bf(v.w);
        ((ushort4*)xb)[i] = o;
    }
}

// prep: W^T concat [v|k|q] -> bf16 [1536][256]; bias concat f32 [1536]
__global__ __launch_bounds__(256) void prep_w(
    const float* __restrict__ Wv, const float* __restrict__ bv,
    const float* __restrict__ Wk, const float* __restrict__ bk,
    const float* __restrict__ Wq, const float* __restrict__ bq,
    u16* __restrict__ Wtb, float* __restrict__ biascat) {
    int i = blockIdx.x * 256 + threadIdx.x;
    if (i < 1536 * 256) {
        int n = i >> 8, k = i & 255;
        const float* W = (n < 512) ? Wv : ((n < 1024) ? Wk : Wq);
        Wtb[i] = f2bf(W[k * 512 + (n & 511)]);         // Wtb[n][k] = W[k][n%512]
    }
    if (i < 1536) {
        biascat[i] = (i < 512) ? bv[i] : ((i < 1024) ? bk[i - 512] : bq[i - 1024]);
    }
}

// ---------------------------------------------------------------------------
// BMx128-tile bf16 MFMA GEMM, both operands K-contiguous row-major.
// C[i][j] = sum_k A[i][k] * Bt[j][k].  BM in {128, 64}.
// SWZ: flat 1D grid, XCD-bijective decode (batch b -> XCD b&7).
// EPI 0: qkv (bias+relu, *SCALE for cols>=1024, bf16)  EPI 1: bf16 store
// EPI 2: relu + f32 store
template<int EPI, int BM, int SWZ>
__global__ __launch_bounds__(256) void gemm_t(
    const u16* __restrict__ A, int lda, long sA,
    const u16* __restrict__ Bt, int ldb, long sB,
    void* __restrict__ Cv, int ldc, long sC,
    int K, const float* __restrict__ bias, int gx, int gy) {
    __shared__ u16 lA[BM * 32];
    __shared__ u16 lB[128 * 32];
    const int t = threadIdx.x;
    const int lane = t & 63;
    const int w = t >> 6;

    int b, bxi, byi;
    if (SWZ) {
        // grid = NB * gx * gy (NB divisible by 8). consecutive hw wgids
        // round-robin XCDs; give XCD x the batches {x, x+8, x+16, x+24}.
        int f = (int)blockIdx.x;
        int per = gx * gy;
        int j = f >> 3;
        b = (f & 7) + 8 * (j / per);
        int r = j % per;
        bxi = r % gx; byi = r / gx;
    } else {
        b = blockIdx.z; bxi = blockIdx.x; byi = blockIdx.y;
    }

    const u16* Ab = A + (long)b * sA;
    const u16* Bb = Bt + (long)b * sB;
    const int bm = bxi * BM, bn = byi * 128;

    // staging: thread t loads 16B chunk (t&3) of row (t>>2)
    const int srow = t >> 2;
    const int soff = (t & 3) * 8;
    const u16* gA0 = Ab + (long)(bm + srow) * lda + soff;
    const u16* gA1 = Ab + (long)(bm + srow + 64) * lda + soff;   // BM==128 only
    const u16* gB0 = Bb + (long)(bn + srow) * ldb + soff;
    const u16* gB1 = Bb + (long)(bn + srow + 64) * ldb + soff;

    constexpr int NJ = (BM == 128) ? 4 : 2;                 // col frags / wave
    const int wr = (BM == 128) ? (w >> 1) * 64 : 0;         // wave row origin
    const int wc = (BM == 128) ? (w & 1) * 64 : w * 32;     // wave col origin
    const int frow = lane & 15, fk = (lane >> 4) * 8;

    f32x4 acc[4][NJ] = {};

    for (int k0 = 0; k0 < K; k0 += 32) {
        __syncthreads();
        g2lds16(gA0 + k0, &lA[t * 8]);
        if (BM == 128) g2lds16(gA1 + k0, &lA[2048 + t * 8]);
        g2lds16(gB0 + k0, &lB[t * 8]);
        g2lds16(gB1 + k0, &lB[2048 + t * 8]);
        __syncthreads();

        bf16x8 af[4], bfr[NJ];
#pragma unroll
        for (int i = 0; i < 4; ++i)
            af[i] = *(const bf16x8*)&lA[(wr + i * 16 + frow) * 32 + fk];
#pragma unroll
        for (int j = 0; j < NJ; ++j)
            bfr[j] = *(const bf16x8*)&lB[(wc + j * 16 + frow) * 32 + fk];
#pragma unroll
        for (int i = 0; i < 4; ++i)
#pragma unroll
            for (int j = 0; j < NJ; ++j)
                acc[i][j] = __builtin_amdgcn_mfma_f32_16x16x32_bf16(
                    af[i], bfr[j], acc[i][j], 0, 0, 0);
    }

    // epilogue: C/D map col=lane&15, row=(lane>>4)*4+reg  [m89-verified]
    const int crow0 = bm + wr + (lane >> 4) * 4;
    const int ccol0 = bn + wc + (lane & 15);
#pragma unroll
    for (int i = 0; i < 4; ++i) {
#pragma unroll
        for (int j = 0; j < NJ; ++j) {
            int col = ccol0 + j * 16;
#pragma unroll
            for (int r = 0; r < 4; ++r) {
                int row = crow0 + i * 16 + r;
                float v = acc[i][j][r];
                if (EPI == 0) {
                    v += bias[col];
                    v = v > 0.0f ? v : 0.0f;
                    if (col >= 1024) v *= SCALEF;      // fold SCALE into q
                    ((u16*)Cv)[(long)b * sC + (long)row * ldc + col] = f2bf(v);
                } else if (EPI == 1) {
                    ((u16*)Cv)[(long)b * sC + (long)row * ldc + col] = f2bf(v);
                } else {
                    ((float*)Cv)[(long)b * sC + (long)row * ldc + col] =
                        v > 0.0f ? v : 0.0f;
                }
            }
        }
    }
}

// ---------------------------------------------------------------------------
// v [b][n][h] (inside qkv, cols 0..511) -> vt [b][h][n]   (bf16)
__global__ __launch_bounds__(256) void transpose_v(const u16* __restrict__ qkv,
                                                   u16* __restrict__ vt) {
    __shared__ u16 tile[64][72];
    const int t = threadIdx.x;
    const int b = blockIdx.z;
    const int n0 = blockIdx.x * 64, h0 = blockIdx.y * 64;
    const u16* src = qkv + (long)(b * NSEQ + n0) * 1536 + h0;
#pragma unroll
    for (int it = 0; it < 2; ++it) {
        int n = (t >> 3) + it * 32;
        int hc = (t & 7) * 8;
        *(bf16x8*)&tile[n][hc] = *(const bf16x8*)&src[(long)n * 1536 + hc];
    }
    __syncthreads();
    u16* dst = vt + ((long)b * HID + h0) * NSEQ + n0;
#pragma unroll
    for (int it = 0; it < 2; ++it) {
        int h = (t >> 3) + it * 32;
        int nc = (t & 7) * 8;
        bf16x8 v;
#pragma unroll
        for (int j = 0; j < 8; ++j) v[j] = (short)tile[nc + j][h];
        *(bf16x8*)&dst[(long)h * NSEQ + nc] = v;
    }
}

// ---------------------------------------------------------------------------
// one block per score row: masked softmax IN PLACE on bf16 SP buffer
__global__ __launch_bounds__(256) void softmax_mask(
    u16* __restrict__ SP, const float* __restrict__ mask) {
    const long row = blockIdx.x;
    const int t = threadIdx.x;
    ushort4 sv = ((const ushort4*)(SP + row * NSEQ))[t];
    float4 mv = ((const float4*)(mask + row * NSEQ))[t];
    float l0 = mv.x * bf2f(sv.x) - NEGC * (1.0f - mv.x);
    float l1 = mv.y * bf2f(sv.y) - NEGC * (1.0f - mv.y);
    float l2 = mv.z * bf2f(sv.z) - NEGC * (1.0f - mv.z);
    float l3 = mv.w * bf2f(sv.w) - NEGC * (1.0f - mv.w);

    float mx = fmaxf(fmaxf(l0, l1), fmaxf(l2, l3));
#pragma unroll
    for (int off = 32; off; off >>= 1) mx = fmaxf(mx, __shfl_xor(mx, off));
    __shared__ float redm[4];
    if ((t & 63) == 0) redm[t >> 6] = mx;
    __syncthreads();
    mx = fmaxf(fmaxf(redm[0], redm[1]), fmaxf(redm[2], redm[3]));

    float e0 = __expf(l0 - mx), e1 = __expf(l1 - mx);
    float e2 = __expf(l2 - mx), e3 = __expf(l3 - mx);
    float sum = (e0 + e1) + (e2 + e3);
#pragma unroll
    for (int off = 32; off; off >>= 1) sum += __shfl_xor(sum, off);
    __shared__ float reds[4];
    if ((t & 63) == 0) reds[t >> 6] = sum;
    __syncthreads();
    sum = (reds[0] + reds[1]) + (reds[2] + reds[3]);

    float inv = 1.0f / sum;
    ushort4 o;
    o.x = f2bf(e0 * inv); o.y = f2bf(e1 * inv);
    o.z = f2bf(e2 * inv); o.w = f2bf(e3 * inv);
    ((ushort4*)(SP + row * NSEQ))[t] = o;
}

// ---------------------------------------------------------------------------
extern "C" void kernel_launch(void* const* d_in, const int* in_sizes, int n_in,
                              void* d_out, int out_size, void* d_ws, size_t ws_size,
                              hipStream_t stream) {
    const float* x    = (const float*)d_in[0];
    const float* mask = (const float*)d_in[1];
    const float* Wv   = (const float*)d_in[2];
    const float* bv   = (const float*)d_in[3];
    const float* Wk   = (const float*)d_in[4];
    const float* bk   = (const float*)d_in[5];
    const float* Wq   = (const float*)d_in[6];
    const float* bq   = (const float*)d_in[7];
    float* out = (float*)d_out;

    char* ws = (char*)d_ws;
    u16*   xb      = (u16*)ws;   ws += (long)NBAT * NSEQ * DIN * 2;      // 16 MB
    u16*   Wtb     = (u16*)ws;   ws += (long)1536 * 256 * 2;             // 768 KB
    float* biascat = (float*)ws; ws += 1536 * 4;
    u16*   qkv     = (u16*)ws;   ws += (long)NBAT * NSEQ * 1536 * 2;     // 96 MB
    u16*   vt      = (u16*)ws;   ws += (long)NBAT * HID * NSEQ * 2;     // 32 MB
    u16*   SP      = (u16*)ws;   ws += (long)NBAT * NSEQ * NSEQ * 2;    // 64 MB (S then P in place)

    prep_x<<<8192, 256, 0, stream>>>(x, xb);
    prep_w<<<1536, 256, 0, stream>>>(Wv, bv, Wk, bk, Wq, bq, Wtb, biascat);

    // qkv projections: [32768,256] x [1536,256]^T -> [32768,1536] bf16
    gemm_t<0, 128, 0><<<dim3(256, 12, 1), 256, 0, stream>>>(
        xb, 256, 0L, Wtb, 256, 0L, qkv, 1536, 0L, 256, biascat, 0, 0);

    transpose_v<<<dim3(16, 8, NBAT), 256, 0, stream>>>(qkv, vt);

    const long sQKV = (long)NSEQ * 1536;
    // scores: per-batch [1024,512] x [1024,512]^T -> SP [1024,1024] bf16
    gemm_t<1, 128, 1><<<NBAT * 8 * 8, 256, 0, stream>>>(
        qkv + 1024, 1536, sQKV, qkv + 512, 1536, sQKV,
        SP, NSEQ, (long)NSEQ * NSEQ, 512, nullptr, 8, 8);

    // masked softmax in place: SP(scores) -> SP(probs)
    softmax_mask<<<NBAT * NSEQ, 256, 0, stream>>>(SP, mask);

    // out: per-batch [1024,1024] x [512,1024]^T -> [1024,512] f32, relu
    gemm_t<2, 64, 1><<<NBAT * 16 * 4, 256, 0, stream>>>(
        SP, NSEQ, (long)NSEQ * NSEQ, vt, NSEQ, (long)HID * NSEQ,
        out, HID, (long)NSEQ * HID, NSEQ, nullptr, 16, 4);
}

// Round 5
// 411.090 us; speedup vs baseline: 1.0846x; 1.0375x over previous
//
#include <hip/hip_runtime.h>
#include <hip/hip_bf16.h>

#define DIN   256
#define HID   512
#define NBAT  32
#define NSEQ  1024
#define SCALEF (1.0f / 2304.0f)
#define NEGC  9e15f

typedef __attribute__((ext_vector_type(4))) float f32x4;
typedef __attribute__((ext_vector_type(8))) short bf16x8;
typedef unsigned short u16;

__device__ __forceinline__ u16 f2bf(float f) {
    union { float f; unsigned u; } v; v.f = f;
    unsigned r = v.u + 0x7fffu + ((v.u >> 16) & 1u);   // RTNE
    return (u16)(r >> 16);
}

__device__ __forceinline__ float bf2f(u16 b) {
    union { unsigned u; float f; } v; v.u = ((unsigned)b) << 16;
    return v.f;
}

__device__ __forceinline__ void g2lds16(const void* g, void* l) {
    __builtin_amdgcn_global_load_lds(
        (const __attribute__((address_space(1))) void*)g,
        (__attribute__((address_space(3))) void*)l,
        16, 0, 0);
}

// ---------------------------------------------------------------------------
// prep: x (f32) -> bf16
__global__ __launch_bounds__(256) void prep_x(const float* __restrict__ x,
                                              u16* __restrict__ xb) {
    long i = (long)blockIdx.x * 256 + threadIdx.x;     // float4 index
    const long n4 = (long)NBAT * NSEQ * DIN / 4;
    if (i < n4) {
        float4 v = ((const float4*)x)[i];
        ushort4 o;
        o.x = f2bf(v.x); o.y = f2bf(v.y); o.z = f2bf(v.z); o.w = f2bf(v.w);
        ((ushort4*)xb)[i] = o;
    }
}

// prep: W^T concat [v|k|q] -> bf16 [1536][256]; bias concat f32 [1536]
__global__ __launch_bounds__(256) void prep_w(
    const float* __restrict__ Wv, const float* __restrict__ bv,
    const float* __restrict__ Wk, const float* __restrict__ bk,
    const float* __restrict__ Wq, const float* __restrict__ bq,
    u16* __restrict__ Wtb, float* __restrict__ biascat) {
    int i = blockIdx.x * 256 + threadIdx.x;
    if (i < 1536 * 256) {
        int n = i >> 8, k = i & 255;
        const float* W = (n < 512) ? Wv : ((n < 1024) ? Wk : Wq);
        Wtb[i] = f2bf(W[k * 512 + (n & 511)]);         // Wtb[n][k] = W[k][n%512]
    }
    if (i < 1536) {
        biascat[i] = (i < 512) ? bv[i] : ((i < 1024) ? bk[i - 512] : bq[i - 1024]);
    }
}

// ---------------------------------------------------------------------------
// 128x128-tile, BK=64 bf16 MFMA GEMM. Both operands K-contiguous row-major.
// C[i][j] = sum_k A[i][k] * Bt[j][k].  K multiple of 64.
// T2 both-sides swizzle (m201/m204 pattern): LDS[r][chunk c] = G[r][c ^ (r&7)]
// staged via pre-swizzled global source (gload_lds dest stays lane-linear);
// ds_read at chunk (kc ^ (r&7)).  ~2-way conflicts (free) instead of 16-way.
// EPI 0: qkv (bias+relu, *SCALE for cols>=1024, bf16)  EPI 1: bf16 store
// EPI 2: relu + f32 store
template<int EPI, int SWZ>
__global__ __launch_bounds__(256) void gemm_t(
    const u16* __restrict__ A, int lda, long sA,
    const u16* __restrict__ Bt, int ldb, long sB,
    void* __restrict__ Cv, int ldc, long sC,
    int K, const float* __restrict__ bias, int gx, int gy) {
    __shared__ u16 lA[128 * 64];
    __shared__ u16 lB[128 * 64];
    const int t = threadIdx.x;
    const int lane = t & 63;
    const int w = t >> 6;

    int b, bxi, byi;
    if (SWZ) {
        // flat grid = NBAT * gx * gy; XCD-bijective: XCD x owns batches x+8j
        int f = (int)blockIdx.x;
        int per = gx * gy;
        int j = f >> 3;
        b = (f & 7) + 8 * (j / per);
        int r = j % per;
        bxi = r % gx; byi = r / gx;
    } else {
        b = blockIdx.z; bxi = blockIdx.x; byi = blockIdx.y;
    }

    const u16* Ab = A + (long)b * sA;
    const u16* Bb = Bt + (long)b * sB;
    const int bm = bxi * 128, bn = byi * 128;

    // staging: pass p, thread t covers LDS row (p*32 + t>>3), 16B chunk (t&7);
    // global source chunk is XOR-swizzled so linear LDS dest lands swizzled.
    const int srow = t >> 3;                          // 0..31
    const int csrc = ((t & 7) ^ (srow & 7)) * 8;      // elems
    const u16* gA0 = Ab + (long)(bm + srow) * lda + csrc;
    const u16* gB0 = Bb + (long)(bn + srow) * ldb + csrc;

    const int wr = (w >> 1) * 64, wc = (w & 1) * 64;  // wave sub-tile origin
    const int frow = lane & 15;                       // fragment row in 16x16
    const int kq = lane >> 4;                         // k-quarter 0..3

    f32x4 acc[4][4] = {};

    for (int k0 = 0; k0 < K; k0 += 64) {
        __syncthreads();
#pragma unroll
        for (int p = 0; p < 4; ++p) {
            g2lds16(gA0 + (long)p * 32 * lda + k0, &lA[p * 2048 + t * 8]);
            g2lds16(gB0 + (long)p * 32 * ldb + k0, &lB[p * 2048 + t * 8]);
        }
        __syncthreads();   // compiler drains vmcnt before barrier

#pragma unroll
        for (int kk = 0; kk < 2; ++kk) {
            const int sc = ((kk * 4 + kq) ^ (frow & 7)) * 8;   // swizzled chunk
            bf16x8 af[4], bfr[4];
#pragma unroll
            for (int i = 0; i < 4; ++i)
                af[i] = *(const bf16x8*)&lA[(wr + i * 16 + frow) * 64 + sc];
#pragma unroll
            for (int j = 0; j < 4; ++j)
                bfr[j] = *(const bf16x8*)&lB[(wc + j * 16 + frow) * 64 + sc];
#pragma unroll
            for (int i = 0; i < 4; ++i)
#pragma unroll
                for (int j = 0; j < 4; ++j)
                    acc[i][j] = __builtin_amdgcn_mfma_f32_16x16x32_bf16(
                        af[i], bfr[j], acc[i][j], 0, 0, 0);
        }
    }

    // epilogue: C/D map col=lane&15, row=(lane>>4)*4+reg  [m89-verified]
    const int crow0 = bm + wr + (lane >> 4) * 4;
    const int ccol0 = bn + wc + (lane & 15);
#pragma unroll
    for (int i = 0; i < 4; ++i) {
#pragma unroll
        for (int j = 0; j < 4; ++j) {
            int col = ccol0 + j * 16;
#pragma unroll
            for (int r = 0; r < 4; ++r) {
                int row = crow0 + i * 16 + r;
                float v = acc[i][j][r];
                if (EPI == 0) {
                    v += bias[col];
                    v = v > 0.0f ? v : 0.0f;
                    if (col >= 1024) v *= SCALEF;      // fold SCALE into q
                    ((u16*)Cv)[(long)b * sC + (long)row * ldc + col] = f2bf(v);
                } else if (EPI == 1) {
                    ((u16*)Cv)[(long)b * sC + (long)row * ldc + col] = f2bf(v);
                } else {
                    ((float*)Cv)[(long)b * sC + (long)row * ldc + col] =
                        v > 0.0f ? v : 0.0f;
                }
            }
        }
    }
}

// ---------------------------------------------------------------------------
// v [b][n][h] (inside qkv, cols 0..511) -> vt [b][h][n]   (bf16)
__global__ __launch_bounds__(256) void transpose_v(const u16* __restrict__ qkv,
                                                   u16* __restrict__ vt) {
    __shared__ u16 tile[64][72];
    const int t = threadIdx.x;
    const int b = blockIdx.z;
    const int n0 = blockIdx.x * 64, h0 = blockIdx.y * 64;
    const u16* src = qkv + (long)(b * NSEQ + n0) * 1536 + h0;
#pragma unroll
    for (int it = 0; it < 2; ++it) {
        int n = (t >> 3) + it * 32;
        int hc = (t & 7) * 8;
        *(bf16x8*)&tile[n][hc] = *(const bf16x8*)&src[(long)n * 1536 + hc];
    }
    __syncthreads();
    u16* dst = vt + ((long)b * HID + h0) * NSEQ + n0;
#pragma unroll
    for (int it = 0; it < 2; ++it) {
        int h = (t >> 3) + it * 32;
        int nc = (t & 7) * 8;
        bf16x8 v;
#pragma unroll
        for (int j = 0; j < 8; ++j) v[j] = (short)tile[nc + j][h];
        *(bf16x8*)&dst[(long)h * NSEQ + nc] = v;
    }
}

// ---------------------------------------------------------------------------
// one block per score row: masked softmax IN PLACE on bf16 SP buffer
__global__ __launch_bounds__(256) void softmax_mask(
    u16* __restrict__ SP, const float* __restrict__ mask) {
    const long row = blockIdx.x;
    const int t = threadIdx.x;
    ushort4 sv = ((const ushort4*)(SP + row * NSEQ))[t];
    float4 mv = ((const float4*)(mask + row * NSEQ))[t];
    float l0 = mv.x * bf2f(sv.x) - NEGC * (1.0f - mv.x);
    float l1 = mv.y * bf2f(sv.y) - NEGC * (1.0f - mv.y);
    float l2 = mv.z * bf2f(sv.z) - NEGC * (1.0f - mv.z);
    float l3 = mv.w * bf2f(sv.w) - NEGC * (1.0f - mv.w);

    float mx = fmaxf(fmaxf(l0, l1), fmaxf(l2, l3));
#pragma unroll
    for (int off = 32; off; off >>= 1) mx = fmaxf(mx, __shfl_xor(mx, off));
    __shared__ float redm[4];
    if ((t & 63) == 0) redm[t >> 6] = mx;
    __syncthreads();
    mx = fmaxf(fmaxf(redm[0], redm[1]), fmaxf(redm[2], redm[3]));

    float e0 = __expf(l0 - mx), e1 = __expf(l1 - mx);
    float e2 = __expf(l2 - mx), e3 = __expf(l3 - mx);
    float sum = (e0 + e1) + (e2 + e3);
#pragma unroll
    for (int off = 32; off; off >>= 1) sum += __shfl_xor(sum, off);
    __shared__ float reds[4];
    if ((t & 63) == 0) reds[t >> 6] = sum;
    __syncthreads();
    sum = (reds[0] + reds[1]) + (reds[2] + reds[3]);

    float inv = 1.0f / sum;
    ushort4 o;
    o.x = f2bf(e0 * inv); o.y = f2bf(e1 * inv);
    o.z = f2bf(e2 * inv); o.w = f2bf(e3 * inv);
    ((ushort4*)(SP + row * NSEQ))[t] = o;
}

// ---------------------------------------------------------------------------
extern "C" void kernel_launch(void* const* d_in, const int* in_sizes, int n_in,
                              void* d_out, int out_size, void* d_ws, size_t ws_size,
                              hipStream_t stream) {
    const float* x    = (const float*)d_in[0];
    const float* mask = (const float*)d_in[1];
    const float* Wv   = (const float*)d_in[2];
    const float* bv   = (const float*)d_in[3];
    const float* Wk   = (const float*)d_in[4];
    const float* bk   = (const float*)d_in[5];
    const float* Wq   = (const float*)d_in[6];
    const float* bq   = (const float*)d_in[7];
    float* out = (float*)d_out;

    char* ws = (char*)d_ws;
    u16*   xb      = (u16*)ws;   ws += (long)NBAT * NSEQ * DIN * 2;      // 16 MB
    u16*   Wtb     = (u16*)ws;   ws += (long)1536 * 256 * 2;             // 768 KB
    float* biascat = (float*)ws; ws += 1536 * 4;
    u16*   qkv     = (u16*)ws;   ws += (long)NBAT * NSEQ * 1536 * 2;     // 96 MB
    u16*   vt      = (u16*)ws;   ws += (long)NBAT * HID * NSEQ * 2;     // 32 MB
    u16*   SP      = (u16*)ws;   ws += (long)NBAT * NSEQ * NSEQ * 2;    // 64 MB (S then P in place)

    prep_x<<<8192, 256, 0, stream>>>(x, xb);
    prep_w<<<1536, 256, 0, stream>>>(Wv, bv, Wk, bk, Wq, bq, Wtb, biascat);

    // qkv projections: [32768,256] x [1536,256]^T -> [32768,1536] bf16
    gemm_t<0, 0><<<dim3(256, 12, 1), 256, 0, stream>>>(
        xb, 256, 0L, Wtb, 256, 0L, qkv, 1536, 0L, 256, biascat, 0, 0);

    transpose_v<<<dim3(16, 8, NBAT), 256, 0, stream>>>(qkv, vt);

    const long sQKV = (long)NSEQ * 1536;
    // scores: per-batch [1024,512] x [1024,512]^T -> SP [1024,1024] bf16
    gemm_t<1, 1><<<NBAT * 8 * 8, 256, 0, stream>>>(
        qkv + 1024, 1536, sQKV, qkv + 512, 1536, sQKV,
        SP, NSEQ, (long)NSEQ * NSEQ, 512, nullptr, 8, 8);

    // masked softmax in place: SP(scores) -> SP(probs)
    softmax_mask<<<NBAT * NSEQ, 256, 0, stream>>>(SP, mask);

    // out: per-batch [1024,1024] x [512,1024]^T -> [1024,512] f32, relu
    gemm_t<2, 1><<<NBAT * 8 * 4, 256, 0, stream>>>(
        SP, NSEQ, (long)NSEQ * NSEQ, vt, NSEQ, (long)HID * NSEQ,
        out, HID, (long)NSEQ * HID, NSEQ, nullptr, 8, 4);
}